// Round 6
// baseline (335.338 us; speedup 1.0000x reference)
//
#include <hip/hip_runtime.h>
#include <hip/hip_bf16.h>

// Problem constants: N=20000 nodes, K=32 nbrs, C=128, H=256
#define NN    20000
#define KNN   32
#define CIN   128
#define HD    256
#define EE    (NN * KNN)        // 640000 edges
#define NB    20                // nodes per ec_main block
#define NBLK  (NN / NB)         // 1000 blocks
#define PZB   (NN / 32)         // 625 pz blocks

typedef __bf16 bf16x8_t __attribute__((ext_vector_type(8)));
typedef __bf16 bf16x4_t __attribute__((ext_vector_type(4)));
typedef float  f32x4_t  __attribute__((ext_vector_type(4)));

// Fused prep (2 kernels total):
// blocks 0..624: per-node precompute of both GEMM1 halves (senders repeat, so
//   the 42 GF edge-GEMM1 collapses to 2.6 GF of node-GEMM):
//     Pq[n][f] = sum_k X[n][k]*(W1a-W1b)[k][f] + b1[f]   (fp32)
//     Zq[n][f] = sum_k X[n][k]*W1b[k][f]                 (bf16)
// blocks 625..752: w2t[n*256+k] = bf16(W2[k][n]).
__global__ __launch_bounds__(512, 1) void ec_pz(
    const float* __restrict__ nf, const float* __restrict__ W1,
    const float* __restrict__ W2, const float* __restrict__ b1,
    float* __restrict__ Pq, __bf16* __restrict__ Zq, __bf16* __restrict__ w2t)
{
    __shared__ __attribute__((aligned(16))) float ldsT[32 * 256];   // 32 KB transpose buf

    const int bid = blockIdx.x;
    const int tid = threadIdx.x;

    if (bid >= PZB) {                                // W2 transpose tail blocks
        int idx = (bid - PZB) * 512 + tid;           // 0..65535
        int k = idx >> 8, n = idx & 255;
        w2t[n * 256 + k] = (__bf16)W2[k * 256 + n];
        return;
    }

    const int lane = tid & 63;
    const int wave = tid >> 6;
    const int qrow = lane >> 4;
    const int lcol = lane & 15;
    const int fsl  = wave * 32;

    // node features for this block's 32 nodes (lane-col = node), fp32 -> bf16
    bf16x8_t xv[2][4];
#pragma unroll
    for (int ni = 0; ni < 2; ++ni) {
        const float* row = nf + (size_t)(bid * 32 + ni * 16 + lcol) * CIN;
#pragma unroll
        for (int c = 0; c < 4; ++c) {
            f32x4_t a = *(const f32x4_t*)(row + c * 32 + qrow * 8);
            f32x4_t b = *(const f32x4_t*)(row + c * 32 + qrow * 8 + 4);
            bf16x8_t x;
#pragma unroll
            for (int j = 0; j < 4; ++j) { x[j] = (__bf16)a[j]; x[j + 4] = (__bf16)b[j]; }
            xv[ni][c] = x;
        }
    }

    float4 bias1[2];
#pragma unroll
    for (int mi = 0; mi < 2; ++mi)
        bias1[mi] = *(const float4*)(b1 + fsl + mi * 16 + qrow * 4);

    // ---- P half: W1a-W1b fragments built inline ----
    {
        f32x4_t ay[2][2];
#pragma unroll
        for (int mi = 0; mi < 2; ++mi)
#pragma unroll
            for (int ni = 0; ni < 2; ++ni)
                ay[mi][ni] = (f32x4_t){0.f, 0.f, 0.f, 0.f};
#pragma unroll
        for (int kt = 0; kt < 4; ++kt) {
            const float* wbase = W1 + (size_t)(kt * 32 + qrow * 8) * 256;
            bf16x8_t wy[2];
#pragma unroll
            for (int mi = 0; mi < 2; ++mi) {
                const int col = fsl + mi * 16 + lcol;
#pragma unroll
                for (int j = 0; j < 8; ++j)
                    wy[mi][j] = (__bf16)(wbase[j * 256 + col]
                                         - wbase[(j + 128) * 256 + col]);
            }
#pragma unroll
            for (int mi = 0; mi < 2; ++mi)
#pragma unroll
                for (int ni = 0; ni < 2; ++ni)
                    ay[mi][ni] = __builtin_amdgcn_mfma_f32_16x16x32_bf16(
                        wy[mi], xv[ni][kt], ay[mi][ni], 0, 0, 0);
        }
        // C-layout: row = feature fsl+mi*16+qrow*4+r, col = node ni*16+lcol
#pragma unroll
        for (int mi = 0; mi < 2; ++mi)
#pragma unroll
            for (int ni = 0; ni < 2; ++ni) {
                f32x4_t v = ay[mi][ni];
                v[0] += bias1[mi].x; v[1] += bias1[mi].y;
                v[2] += bias1[mi].z; v[3] += bias1[mi].w;
                *(f32x4_t*)(ldsT + (ni * 16 + lcol) * 256 + fsl + mi * 16 + qrow * 4) = v;
            }
    }
    __syncthreads();
    {   // coalesced fp32 store of P'
        float4* dst = (float4*)(Pq + (size_t)bid * 32 * 256);
        const float4* src = (const float4*)ldsT;
#pragma unroll
        for (int i = 0; i < 4; ++i)
            dst[tid * 4 + i] = src[tid * 4 + i];
    }
    __syncthreads();   // store-phase reads done before Z overwrites ldsT

    // ---- Z half: W1b fragments built inline ----
    {
        f32x4_t az[2][2];
#pragma unroll
        for (int mi = 0; mi < 2; ++mi)
#pragma unroll
            for (int ni = 0; ni < 2; ++ni)
                az[mi][ni] = (f32x4_t){0.f, 0.f, 0.f, 0.f};
#pragma unroll
        for (int kt = 0; kt < 4; ++kt) {
            const float* wbase = W1 + (size_t)(kt * 32 + qrow * 8 + 128) * 256;
            bf16x8_t wy[2];
#pragma unroll
            for (int mi = 0; mi < 2; ++mi) {
                const int col = fsl + mi * 16 + lcol;
#pragma unroll
                for (int j = 0; j < 8; ++j)
                    wy[mi][j] = (__bf16)wbase[j * 256 + col];
            }
#pragma unroll
            for (int mi = 0; mi < 2; ++mi)
#pragma unroll
                for (int ni = 0; ni < 2; ++ni)
                    az[mi][ni] = __builtin_amdgcn_mfma_f32_16x16x32_bf16(
                        wy[mi], xv[ni][kt], az[mi][ni], 0, 0, 0);
        }
#pragma unroll
        for (int mi = 0; mi < 2; ++mi)
#pragma unroll
            for (int ni = 0; ni < 2; ++ni)
                *(f32x4_t*)(ldsT + (ni * 16 + lcol) * 256 + fsl + mi * 16 + qrow * 4)
                    = az[mi][ni];
    }
    __syncthreads();
    {   // coalesced bf16 store of Z
        const float4* src = (const float4*)ldsT;
        __bf16* dst = Zq + (size_t)bid * 32 * 256;
#pragma unroll
        for (int i = 0; i < 4; ++i) {
            float4 v = src[tid * 4 + i];
            bf16x4_t b = { (__bf16)v.x, (__bf16)v.y, (__bf16)v.z, (__bf16)v.w };
            *(bf16x4_t*)(dst + (size_t)(tid * 4 + i) * 4) = b;
        }
    }
}

// One 8-kt MFMA phase over a 16-edge fragment: assemble h = relu(P+Z) in regs
// (A-frag layout: lane holds H[edge=l&15][k=kt*32+(l>>4)*8+j]) and accumulate.
// kt-granular independence: assemble(kt+1) overlaps MFMA(kt) within the wave.
__device__ __forceinline__ void mfma_phase(
    const bf16x8_t (&zf)[8], const float* __restrict__ pRow, int qrow8,
    const bf16x8_t (&w2f)[8][4], f32x4_t (&acc)[4])
{
#pragma unroll
    for (int kt = 0; kt < 8; ++kt) {
        f32x4_t p0 = *(const f32x4_t*)(pRow + kt * 32 + qrow8);
        f32x4_t p1 = *(const f32x4_t*)(pRow + kt * 32 + qrow8 + 4);
        bf16x8_t zz = zf[kt];
        bf16x8_t h;
#pragma unroll
        for (int j = 0; j < 4; ++j) {
            h[j]     = (__bf16)fmaxf(p0[j] + (float)zz[j],     0.f);
            h[j + 4] = (__bf16)fmaxf(p1[j] + (float)zz[j + 4], 0.f);
        }
#pragma unroll
        for (int ni = 0; ni < 4; ++ni)
            acc[ni] = __builtin_amdgcn_mfma_f32_16x16x32_bf16(
                h, w2f[kt][ni], acc[ni], 0, 0, 0);
    }
}

// Main (round-6 = round-4's barrier-free design + the regalloc fix):
// __launch_bounds__(256, 1) — NOT (256,2): the min-wave=2 bound forced a
// 128/128 arch/AGPR split and spilled (round-4: WRITE 80 MB, MfmaUtil 6%).
// With min-wave=1 the allocator settles ~230 regs / 2 waves/SIMD with zero
// spill, exactly as rounds 3/5 demonstrated at the same footprint.
// 256 thr / 4 waves; wave w owns output-feature slice w*64 (w2f = 128 regs)
// and sweeps all NB nodes. Per node, two 16-edge A-fragments are gathered
// directly from Zq in MFMA fragment layout (16 full 64B lines per load),
// assembled with fp32 P' from LDS, and fed straight to MFMA. Ping-pong
// zfA/zfB = one-phase (~650 cyc) prefetch distance. H never touches LDS;
// zero barriers in the loop; waves fully independent.
__global__ __launch_bounds__(256, 1) void ec_main(
    const __bf16* __restrict__ Zq,       // [NN][HD] bf16
    const int*   __restrict__ senders,   // [EE]
    const float* __restrict__ Pq,        // [NN][HD] fp32 (b1 folded in)
    const __bf16* __restrict__ w2t,      // [256 n][256 k]
    const float* __restrict__ b2,
    float* __restrict__ out)             // [NN][HD] fp32
{
    __shared__ __attribute__((aligned(16))) float ldsP[NB * 256];   // 20 KB fp32 P'

    const int tid  = threadIdx.x;
    const int lane = tid & 63;
    const int wave = tid >> 6;           // 0..3
    const int qrow = lane >> 4;
    const int lcol = lane & 15;
    const int q8   = qrow * 8;
    const int blk  = blockIdx.x;
    const int fs2  = wave * 64;          // this wave's output-feature slice
    const int n0   = blk * NB;

    // ---- cooperative P' load: NB rows x 256 fp32 ----
    {
        const float4* src = (const float4*)(Pq + (size_t)n0 * 256);
        float4* dst = (float4*)ldsP;
#pragma unroll
        for (int i = 0; i < 5; ++i)
            dst[tid + i * 256] = src[tid + i * 256];
    }

    // ---- register-resident W2 slice (64 features): 128 regs ----
    bf16x8_t w2f[8][4];
#pragma unroll
    for (int kt = 0; kt < 8; ++kt)
#pragma unroll
        for (int ni = 0; ni < 4; ++ni)
            w2f[kt][ni] = *(const bf16x8_t*)(w2t + (size_t)(fs2 + ni * 16 + lcol) * 256
                                                 + kt * 32 + q8);
    float bias2[4];
#pragma unroll
    for (int ni = 0; ni < 4; ++ni)
        bias2[ni] = b2[fs2 + ni * 16 + lcol];

    // ---- prologue: gather (n=0, m=0) into zfA; preload sender idx (0, m=1) ----
    bf16x8_t zfA[8], zfB[8];
    {
        int sA = senders[n0 * KNN + lcol];
        const __bf16* zb = Zq + (size_t)sA * HD + q8;
#pragma unroll
        for (int kt = 0; kt < 8; ++kt)
            zfA[kt] = *(const bf16x8_t*)(zb + kt * 32);
    }
    int sB = senders[n0 * KNN + 16 + lcol];

    __syncthreads();   // ldsP published (only barrier in the kernel)

#pragma unroll 1
    for (int n = 0; n < NB; ++n) {
        const float* pRow = ldsP + n * 256;

        // ---- phase m=0: prefetch (n, m=1) into zfB; consume zfA ----
        {
            const __bf16* zb = Zq + (size_t)sB * HD + q8;
#pragma unroll
            for (int kt = 0; kt < 8; ++kt)
                zfB[kt] = *(const bf16x8_t*)(zb + kt * 32);
        }
        int sA2 = 0;
        if (n + 1 < NB) sA2 = senders[(n0 + n + 1) * KNN + lcol];

        f32x4_t acc[4];
#pragma unroll
        for (int ni = 0; ni < 4; ++ni) acc[ni] = (f32x4_t){0.f, 0.f, 0.f, 0.f};
        mfma_phase(zfA, pRow, q8, w2f, acc);

        float pm[4];
#pragma unroll
        for (int ni = 0; ni < 4; ++ni)
            pm[ni] = fmaxf(fmaxf(acc[ni][0], acc[ni][1]),
                           fmaxf(acc[ni][2], acc[ni][3]));

        // ---- phase m=1: prefetch (n+1, m=0) into zfA; consume zfB ----
        if (n + 1 < NB) {
            const __bf16* zb = Zq + (size_t)sA2 * HD + q8;
#pragma unroll
            for (int kt = 0; kt < 8; ++kt)
                zfA[kt] = *(const bf16x8_t*)(zb + kt * 32);
            sB = senders[(n0 + n + 1) * KNN + 16 + lcol];
        }

#pragma unroll
        for (int ni = 0; ni < 4; ++ni) acc[ni] = (f32x4_t){0.f, 0.f, 0.f, 0.f};
        mfma_phase(zfB, pRow, q8, w2f, acc);

        // ---- epilogue: node max over 32 edges (4 in-lane + qrow groups) ----
#pragma unroll
        for (int ni = 0; ni < 4; ++ni) {
            float mx = fmaxf(pm[ni],
                             fmaxf(fmaxf(acc[ni][0], acc[ni][1]),
                                   fmaxf(acc[ni][2], acc[ni][3])));
            mx = fmaxf(mx, __shfl_xor(mx, 16, 64));
            mx = fmaxf(mx, __shfl_xor(mx, 32, 64));
            if (qrow == 0)
                out[(size_t)(n0 + n) * HD + fs2 + ni * 16 + lcol] = mx + bias2[ni];
        }
    }
}

extern "C" void kernel_launch(void* const* d_in, const int* in_sizes, int n_in,
                              void* d_out, int out_size, void* d_ws, size_t ws_size,
                              hipStream_t stream) {
    const float* nf      = (const float*)d_in[0];
    const int*   senders = (const int*)d_in[1];
    // d_in[2] = receivers: implicit (repeat(arange(N), K)), unused
    const float* W1 = (const float*)d_in[3];
    const float* b1 = (const float*)d_in[4];
    const float* W2 = (const float*)d_in[5];
    const float* b2 = (const float*)d_in[6];

    __bf16* w2t = (__bf16*)d_ws;                 // 128 KB [n][k] bf16 W2^T
    __bf16* Zq  = w2t + 256 * 256;               // 10.24 MB bf16 Z = X*W1b
    float*  Pq  = (float*)(Zq + (size_t)NN * HD);// 20.48 MB fp32 P' = X*(W1a-W1b)+b1

    ec_pz<<<PZB + 128, 512, 0, stream>>>(nf, W1, W2, b1, Pq, Zq, w2t);
    ec_main<<<NBLK, 256, 0, stream>>>(Zq, senders, Pq, w2t, b2, (float*)d_out);
}

// Round 8
// 219.368 us; speedup vs baseline: 1.5287x; 1.5287x over previous
//
#include <hip/hip_runtime.h>
#include <hip/hip_bf16.h>

// Problem constants: N=20000 nodes, K=32 nbrs, C=128, H=256
#define NN    20000
#define KNN   32
#define CIN   128
#define HD    256
#define EE    (NN * KNN)        // 640000 edges
#define NT    20                // nodes per ec_main block (1 node per tile)
#define NBLK  (NN / NT)         // 1000 blocks
#define PZB   (NN / 32)         // 625 pz blocks

typedef __bf16 bf16x8_t __attribute__((ext_vector_type(8)));
typedef __bf16 bf16x4_t __attribute__((ext_vector_type(4)));
typedef float  f32x4_t  __attribute__((ext_vector_type(4)));

// Weight prep (tiny, 256 blocks): w1g = frag-ordered W1' = [W1a-W1b ; W1b]
//   w1g[((kt*4+qr)*256+n)*8+j] = W1'[k=kt*32+qr*8+j][n]
//   (chunks 0-15 = receiver half (W1a-W1b), 16-31 = sender half (W1b))
// w2t[n*256+k] = bf16(W2[k][n]).   Coalesced reads (consecutive n per thread).
__global__ void ec_wprep(const float* __restrict__ W1, const float* __restrict__ W2,
                         __bf16* __restrict__ w1g, __bf16* __restrict__ w2t) {
    int idx = blockIdx.x * 256 + threadIdx.x;     // 0..65535
    int k = idx >> 8, n = idx & 255;
    float v = (k < CIN) ? (W1[k * 256 + n] - W1[(k + CIN) * 256 + n])
                        : W1[k * 256 + n];
    int kt = k >> 5, qr = (k >> 3) & 3, j = k & 7;
    w1g[(size_t)((kt * 4 + qr) * 256 + n) * 8 + j] = (__bf16)v;
    w2t[n * 256 + k] = (__bf16)W2[k * 256 + n];
}

// Per-node precompute of both GEMM1 halves (senders repeat, so the 42 GF
// edge-GEMM1 collapses to 2.6 GF of node-GEMM):
//   Pq[n][f] = sum_k X[n][k]*(W1a-W1b)[k][f] + b1[f]   (fp32)
//   Zq[n][f] = sum_k X[n][k]*W1b[k][f]                 (bf16)
// nf read fp32 directly (no nfb pass); W1' fragments read VECTORIZED from w1g
// (round-3's fast path — round 5/6's inline scalar build cost ~12 µs extra).
__global__ __launch_bounds__(512, 1) void ec_pz(
    const float* __restrict__ nf, const __bf16* __restrict__ w1g,
    const float* __restrict__ b1, float* __restrict__ Pq, __bf16* __restrict__ Zq)
{
    __shared__ __attribute__((aligned(16))) float ldsT[32 * 256];   // 32 KB transpose buf

    const int bid  = blockIdx.x;
    const int tid  = threadIdx.x;
    const int lane = tid & 63;
    const int wave = tid >> 6;
    const int qrow = lane >> 4;
    const int lcol = lane & 15;
    const int fsl  = wave * 32;

    // node features for this block's 32 nodes (lane-col = node), fp32 -> bf16
    bf16x8_t xv[2][4];
#pragma unroll
    for (int ni = 0; ni < 2; ++ni) {
        const float* row = nf + (size_t)(bid * 32 + ni * 16 + lcol) * CIN;
#pragma unroll
        for (int c = 0; c < 4; ++c) {
            f32x4_t a = *(const f32x4_t*)(row + c * 32 + qrow * 8);
            f32x4_t b = *(const f32x4_t*)(row + c * 32 + qrow * 8 + 4);
            bf16x8_t x;
#pragma unroll
            for (int j = 0; j < 4; ++j) { x[j] = (__bf16)a[j]; x[j + 4] = (__bf16)b[j]; }
            xv[ni][c] = x;
        }
    }

    float4 bias1[2];
#pragma unroll
    for (int mi = 0; mi < 2; ++mi)
        bias1[mi] = *(const float4*)(b1 + fsl + mi * 16 + qrow * 4);

    // ---- P half (w1g chunks 0..15), +b1 ----
    {
        f32x4_t ay[2][2];
#pragma unroll
        for (int mi = 0; mi < 2; ++mi)
#pragma unroll
            for (int ni = 0; ni < 2; ++ni)
                ay[mi][ni] = (f32x4_t){0.f, 0.f, 0.f, 0.f};
#pragma unroll
        for (int kt = 0; kt < 4; ++kt) {
            bf16x8_t wy[2];
#pragma unroll
            for (int mi = 0; mi < 2; ++mi)
                wy[mi] = *(const bf16x8_t*)(w1g +
                    (size_t)((kt * 4 + qrow) * 256 + fsl + mi * 16 + lcol) * 8);
#pragma unroll
            for (int mi = 0; mi < 2; ++mi)
#pragma unroll
                for (int ni = 0; ni < 2; ++ni)
                    ay[mi][ni] = __builtin_amdgcn_mfma_f32_16x16x32_bf16(
                        wy[mi], xv[ni][kt], ay[mi][ni], 0, 0, 0);
        }
        // C-layout: row = feature fsl+mi*16+qrow*4+r, col = node ni*16+lcol
#pragma unroll
        for (int mi = 0; mi < 2; ++mi)
#pragma unroll
            for (int ni = 0; ni < 2; ++ni) {
                f32x4_t v = ay[mi][ni];
                v[0] += bias1[mi].x; v[1] += bias1[mi].y;
                v[2] += bias1[mi].z; v[3] += bias1[mi].w;
                *(f32x4_t*)(ldsT + (ni * 16 + lcol) * 256 + fsl + mi * 16 + qrow * 4) = v;
            }
    }
    __syncthreads();
    {   // coalesced fp32 store of P'
        float4* dst = (float4*)(Pq + (size_t)bid * 32 * 256);
        const float4* src = (const float4*)ldsT;
#pragma unroll
        for (int i = 0; i < 4; ++i)
            dst[tid * 4 + i] = src[tid * 4 + i];
    }
    __syncthreads();   // store-phase reads done before Z overwrites ldsT

    // ---- Z half (w1g chunks 16..31), no bias ----
    {
        f32x4_t az[2][2];
#pragma unroll
        for (int mi = 0; mi < 2; ++mi)
#pragma unroll
            for (int ni = 0; ni < 2; ++ni)
                az[mi][ni] = (f32x4_t){0.f, 0.f, 0.f, 0.f};
#pragma unroll
        for (int kt = 0; kt < 4; ++kt) {
            bf16x8_t wy[2];
#pragma unroll
            for (int mi = 0; mi < 2; ++mi)
                wy[mi] = *(const bf16x8_t*)(w1g +
                    (size_t)((16 + kt * 4 + qrow) * 256 + fsl + mi * 16 + lcol) * 8);
#pragma unroll
            for (int mi = 0; mi < 2; ++mi)
#pragma unroll
                for (int ni = 0; ni < 2; ++ni)
                    az[mi][ni] = __builtin_amdgcn_mfma_f32_16x16x32_bf16(
                        wy[mi], xv[ni][kt], az[mi][ni], 0, 0, 0);
        }
#pragma unroll
        for (int mi = 0; mi < 2; ++mi)
#pragma unroll
            for (int ni = 0; ni < 2; ++ni)
                *(f32x4_t*)(ldsT + (ni * 16 + lcol) * 256 + fsl + mi * 16 + qrow * 4)
                    = az[mi][ni];
    }
    __syncthreads();
    {   // coalesced bf16 store of Z
        const float4* src = (const float4*)ldsT;
        __bf16* dst = Zq + (size_t)bid * 32 * 256;
#pragma unroll
        for (int i = 0; i < 4; ++i) {
            float4 v = src[tid * 4 + i];
            bf16x4_t b = { (__bf16)v.x, (__bf16)v.y, (__bf16)v.z, (__bf16)v.w };
            *(bf16x4_t*)(dst + (size_t)(tid * 4 + i) * 4) = b;
        }
    }
}

// Main (round-7 = round-5's proven structure + T5 setprio around the MFMA
// cluster). 256 thr / 4 waves; 1-node tiles (32 edges); wave w owns
// output-feature slice w*64 (w2f = 128 AGPRs) and assembles slice w*64 of H.
// LDS 52 KB -> 2 blocks/CU at 2 waves/SIMD (112 arch + 128 AGPR, no spill).
// setprio(1) during GEMM2 breaks the two co-resident blocks' convoy
// phase-lock: the wave in its MFMA burst wins issue slots over the wave in
// epi/assemble, so bursts alternate instead of synchronizing.
__global__ __launch_bounds__(256, 1) void ec_main(
    const __bf16* __restrict__ Zq,       // [NN][HD] bf16
    const int*   __restrict__ senders,   // [EE]
    const float* __restrict__ Pq,        // [NN][HD] fp32 (b1 folded in)
    const __bf16* __restrict__ w2t,      // [256 n][256 k]
    const float* __restrict__ b2,
    float* __restrict__ out)             // [NN][HD] fp32
{
    __shared__ __attribute__((aligned(16))) __bf16 ldsH[2][8192];   // 2x16 KB H dbuf
    __shared__ __attribute__((aligned(16))) float  ldsP[NT * 256];  // 20 KB fp32 P'

    const int tid  = threadIdx.x;
    const int lane = tid & 63;
    const int wave = tid >> 6;           // 0..3
    const int qrow = lane >> 4;
    const int lcol = lane & 15;
    const int blk  = blockIdx.x;
    const int fsl  = wave * 64;          // this wave's feature slice (assemble + GEMM2)
    const int e5   = lane & 31;          // edge id for gather/senders
    const int half = lane >> 5;          // feature half within slice (assemble)
    const int fb   = fsl + half * 32;    // assemble feature base (32-aligned)
    const int ktb  = fb >> 5;            // frag kt for assemble writes
    const int n0   = blk * NT;

    // ---- cooperative P' load: NT rows x 256 fp32 ----
    {
        const float4* src = (const float4*)(Pq + (size_t)n0 * 256);
        float4* dst = (float4*)ldsP;
#pragma unroll
        for (int i = 0; i < 5; ++i)
            dst[tid + i * 256] = src[tid + i * 256];
    }

    // ---- register-resident W2 slice (64 features): 128 regs ----
    bf16x8_t w2f[8][4];
#pragma unroll
    for (int kt = 0; kt < 8; ++kt)
#pragma unroll
        for (int ni = 0; ni < 4; ++ni)
            w2f[kt][ni] = *(const bf16x8_t*)(w2t + (size_t)(fsl + ni * 16 + lcol) * 256
                                                 + kt * 32 + qrow * 8);
    float bias2[4];
#pragma unroll
    for (int ni = 0; ni < 4; ++ni)
        bias2[ni] = b2[fsl + ni * 16 + lcol];

    // ---- prologue: gather Z(0); rolling sender-idx prefetch (2 regs) ----
    bf16x8_t zf[4];
    {
        int s0 = senders[n0 * KNN + e5];
        const __bf16* zb = Zq + (size_t)s0 * HD + fb;
#pragma unroll
        for (int c = 0; c < 4; ++c)
            zf[c] = *(const bf16x8_t*)(zb + c * 8);
    }
    int sn = senders[(n0 + 1) * KNN + e5];    // idx for tile 1

    __syncthreads();   // ldsP ready

    // ---- assemble H(0) -> ldsH[0]: h = relu(P'[node0] + Z) ----
    {
        const float* pf = ldsP + 0 * 256 + fb;
#pragma unroll
        for (int c = 0; c < 4; ++c) {
            f32x4_t p0 = *(const f32x4_t*)(pf + c * 8);
            f32x4_t p1 = *(const f32x4_t*)(pf + c * 8 + 4);
            bf16x8_t h;
#pragma unroll
            for (int j = 0; j < 4; ++j) {
                h[j]     = (__bf16)fmaxf(p0[j] + (float)zf[c][j],     0.f);
                h[j + 4] = (__bf16)fmaxf(p1[j] + (float)zf[c][j + 4], 0.f);
            }
            *(bf16x8_t*)(&ldsH[0][0] + (size_t)((ktb * 4 + c) * 32 + e5) * 8) = h;
        }
    }
    __syncthreads();   // ldsH[0] published

#pragma unroll 1
    for (int t = 0; t < NT; ++t) {
        const int cur = t & 1;

        // ---- gather Z(t+1) (latency covered by GEMM2) ----
        if (t + 1 < NT) {
            const __bf16* zb = Zq + (size_t)sn * HD + fb;
#pragma unroll
            for (int c = 0; c < 4; ++c)
                zf[c] = *(const bf16x8_t*)(zb + c * 8);
        }
        int sn2 = 0;
        if (t + 2 < NT) sn2 = senders[(n0 + t + 2) * KNN + e5];

        // ---- GEMM2: D = H(32 edges, ldsH[cur]) x W2(64 features, regs), K=256 ----
        f32x4_t acc2[2][4];
#pragma unroll
        for (int mi = 0; mi < 2; ++mi)
#pragma unroll
            for (int ni = 0; ni < 4; ++ni)
                acc2[mi][ni] = (f32x4_t){0.f, 0.f, 0.f, 0.f};
        __builtin_amdgcn_s_setprio(1);   // T5: favor the MFMA-burst wave
#pragma unroll
        for (int kt = 0; kt < 8; ++kt) {
            bf16x8_t af[2];
#pragma unroll
            for (int mi = 0; mi < 2; ++mi)
                af[mi] = *(const bf16x8_t*)(&ldsH[cur][0] +
                    (size_t)((kt * 4 + qrow) * 32 + mi * 16 + lcol) * 8);
#pragma unroll
            for (int mi = 0; mi < 2; ++mi)
#pragma unroll
                for (int ni = 0; ni < 4; ++ni)
                    acc2[mi][ni] = __builtin_amdgcn_mfma_f32_16x16x32_bf16(
                        af[mi], w2f[kt][ni], acc2[mi][ni], 0, 0, 0);
        }
        __builtin_amdgcn_s_setprio(0);

        // ---- epilogue: max over the node's 32 edges, +b2, store ----
#pragma unroll
        for (int ni = 0; ni < 4; ++ni) {
            float mx = -3.402823466e38f;
#pragma unroll
            for (int mi = 0; mi < 2; ++mi)
#pragma unroll
                for (int r = 0; r < 4; ++r)
                    mx = fmaxf(mx, acc2[mi][ni][r]);
            mx = fmaxf(mx, __shfl_xor(mx, 16, 64));
            mx = fmaxf(mx, __shfl_xor(mx, 32, 64));
            if (qrow == 0)
                out[(size_t)(n0 + t) * HD + fsl + ni * 16 + lcol] = mx + bias2[ni];
        }

        // ---- assemble H(t+1) -> ldsH[1-cur] (its last readers, GEMM2(t-1),
        //      finished before barrier(t-1); this runs after it) ----
        if (t + 1 < NT) {
            const float* pf = ldsP + (t + 1) * 256 + fb;
#pragma unroll
            for (int c = 0; c < 4; ++c) {
                f32x4_t p0 = *(const f32x4_t*)(pf + c * 8);
                f32x4_t p1 = *(const f32x4_t*)(pf + c * 8 + 4);
                bf16x8_t h;
#pragma unroll
                for (int j = 0; j < 4; ++j) {
                    h[j]     = (__bf16)fmaxf(p0[j] + (float)zf[c][j],     0.f);
                    h[j + 4] = (__bf16)fmaxf(p1[j] + (float)zf[c][j + 4], 0.f);
                }
                *(bf16x8_t*)(&ldsH[1 - cur][0] + (size_t)((ktb * 4 + c) * 32 + e5) * 8) = h;
            }
        }
        sn = sn2;

        __syncthreads();   // publishes ldsH[1-cur] for tile t+1
    }
}

extern "C" void kernel_launch(void* const* d_in, const int* in_sizes, int n_in,
                              void* d_out, int out_size, void* d_ws, size_t ws_size,
                              hipStream_t stream) {
    const float* nf      = (const float*)d_in[0];
    const int*   senders = (const int*)d_in[1];
    // d_in[2] = receivers: implicit (repeat(arange(N), K)), unused
    const float* W1 = (const float*)d_in[3];
    const float* b1 = (const float*)d_in[4];
    const float* W2 = (const float*)d_in[5];
    const float* b2 = (const float*)d_in[6];

    __bf16* w1g = (__bf16*)d_ws;                 // 128 KB frag-ordered W1'
    __bf16* w2t = w1g + 256 * 256;               // 128 KB [n][k] bf16 W2^T
    __bf16* Zq  = w2t + 256 * 256;               // 10.24 MB bf16 Z = X*W1b
    float*  Pq  = (float*)(Zq + (size_t)NN * HD);// 20.48 MB fp32 P' = X*(W1a-W1b)+b1

    ec_wprep<<<256, 256, 0, stream>>>(W1, W2, w1g, w2t);
    ec_pz<<<PZB, 512, 0, stream>>>(nf, w1g, b1, Pq, Zq);
    ec_main<<<NBLK, 256, 0, stream>>>(Zq, senders, Pq, w2t, b2, (float*)d_out);
}

// Round 9
// 203.341 us; speedup vs baseline: 1.6491x; 1.0788x over previous
//
#include <hip/hip_runtime.h>
#include <hip/hip_bf16.h>

// Problem constants: N=20000 nodes, K=32 nbrs, C=128, H=256
#define NN    20000
#define KNN   32
#define CIN   128
#define HD    256
#define EE    (NN * KNN)        // 640000 edges
#define NT    20                // nodes per ec_main block (1 node per tile)
#define NBLK  (NN / NT)         // 1000 blocks
#define PZB   (NN / 32)         // 625 pz blocks

typedef __bf16 bf16x8_t __attribute__((ext_vector_type(8)));
typedef __bf16 bf16x4_t __attribute__((ext_vector_type(4)));
typedef float  f32x4_t  __attribute__((ext_vector_type(4)));

// Weight prep (tiny, 256 blocks): w1g = frag-ordered W1' = [W1a-W1b ; W1b]
//   w1g[((kt*4+qr)*256+n)*8+j] = W1'[k=kt*32+qr*8+j][n]
//   (chunks 0-15 = receiver half (W1a-W1b), 16-31 = sender half (W1b))
// w2t[n*256+k] = bf16(W2[k][n]).   Coalesced reads (consecutive n per thread).
__global__ void ec_wprep(const float* __restrict__ W1, const float* __restrict__ W2,
                         __bf16* __restrict__ w1g, __bf16* __restrict__ w2t) {
    int idx = blockIdx.x * 256 + threadIdx.x;     // 0..65535
    int k = idx >> 8, n = idx & 255;
    float v = (k < CIN) ? (W1[k * 256 + n] - W1[(k + CIN) * 256 + n])
                        : W1[k * 256 + n];
    int kt = k >> 5, qr = (k >> 3) & 3, j = k & 7;
    w1g[(size_t)((kt * 4 + qr) * 256 + n) * 8 + j] = (__bf16)v;
    w2t[n * 256 + k] = (__bf16)W2[k * 256 + n];
}

// Per-node precompute of both GEMM1 halves (senders repeat, so the 42 GF
// edge-GEMM1 collapses to 2.6 GF of node-GEMM):
//   Pq[n][f] = sum_k X[n][k]*(W1a-W1b)[k][f] + b1[f]   (fp32)
//   Zq[n][f] = sum_k X[n][k]*W1b[k][f]                 (bf16)
__global__ __launch_bounds__(512, 1) void ec_pz(
    const float* __restrict__ nf, const __bf16* __restrict__ w1g,
    const float* __restrict__ b1, float* __restrict__ Pq, __bf16* __restrict__ Zq)
{
    __shared__ __attribute__((aligned(16))) float ldsT[32 * 256];   // 32 KB transpose buf

    const int bid  = blockIdx.x;
    const int tid  = threadIdx.x;
    const int lane = tid & 63;
    const int wave = tid >> 6;
    const int qrow = lane >> 4;
    const int lcol = lane & 15;
    const int fsl  = wave * 32;

    // node features for this block's 32 nodes (lane-col = node), fp32 -> bf16
    bf16x8_t xv[2][4];
#pragma unroll
    for (int ni = 0; ni < 2; ++ni) {
        const float* row = nf + (size_t)(bid * 32 + ni * 16 + lcol) * CIN;
#pragma unroll
        for (int c = 0; c < 4; ++c) {
            f32x4_t a = *(const f32x4_t*)(row + c * 32 + qrow * 8);
            f32x4_t b = *(const f32x4_t*)(row + c * 32 + qrow * 8 + 4);
            bf16x8_t x;
#pragma unroll
            for (int j = 0; j < 4; ++j) { x[j] = (__bf16)a[j]; x[j + 4] = (__bf16)b[j]; }
            xv[ni][c] = x;
        }
    }

    float4 bias1[2];
#pragma unroll
    for (int mi = 0; mi < 2; ++mi)
        bias1[mi] = *(const float4*)(b1 + fsl + mi * 16 + qrow * 4);

    // ---- P half (w1g chunks 0..15), +b1 ----
    {
        f32x4_t ay[2][2];
#pragma unroll
        for (int mi = 0; mi < 2; ++mi)
#pragma unroll
            for (int ni = 0; ni < 2; ++ni)
                ay[mi][ni] = (f32x4_t){0.f, 0.f, 0.f, 0.f};
#pragma unroll
        for (int kt = 0; kt < 4; ++kt) {
            bf16x8_t wy[2];
#pragma unroll
            for (int mi = 0; mi < 2; ++mi)
                wy[mi] = *(const bf16x8_t*)(w1g +
                    (size_t)((kt * 4 + qrow) * 256 + fsl + mi * 16 + lcol) * 8);
#pragma unroll
            for (int mi = 0; mi < 2; ++mi)
#pragma unroll
                for (int ni = 0; ni < 2; ++ni)
                    ay[mi][ni] = __builtin_amdgcn_mfma_f32_16x16x32_bf16(
                        wy[mi], xv[ni][kt], ay[mi][ni], 0, 0, 0);
        }
        // C-layout: row = feature fsl+mi*16+qrow*4+r, col = node ni*16+lcol
#pragma unroll
        for (int mi = 0; mi < 2; ++mi)
#pragma unroll
            for (int ni = 0; ni < 2; ++ni) {
                f32x4_t v = ay[mi][ni];
                v[0] += bias1[mi].x; v[1] += bias1[mi].y;
                v[2] += bias1[mi].z; v[3] += bias1[mi].w;
                *(f32x4_t*)(ldsT + (ni * 16 + lcol) * 256 + fsl + mi * 16 + qrow * 4) = v;
            }
    }
    __syncthreads();
    {   // coalesced fp32 store of P'
        float4* dst = (float4*)(Pq + (size_t)bid * 32 * 256);
        const float4* src = (const float4*)ldsT;
#pragma unroll
        for (int i = 0; i < 4; ++i)
            dst[tid * 4 + i] = src[tid * 4 + i];
    }
    __syncthreads();   // store-phase reads done before Z overwrites ldsT

    // ---- Z half (w1g chunks 16..31), no bias ----
    {
        f32x4_t az[2][2];
#pragma unroll
        for (int mi = 0; mi < 2; ++mi)
#pragma unroll
            for (int ni = 0; ni < 2; ++ni)
                az[mi][ni] = (f32x4_t){0.f, 0.f, 0.f, 0.f};
#pragma unroll
        for (int kt = 0; kt < 4; ++kt) {
            bf16x8_t wy[2];
#pragma unroll
            for (int mi = 0; mi < 2; ++mi)
                wy[mi] = *(const bf16x8_t*)(w1g +
                    (size_t)((16 + kt * 4 + qrow) * 256 + fsl + mi * 16 + lcol) * 8);
#pragma unroll
            for (int mi = 0; mi < 2; ++mi)
#pragma unroll
                for (int ni = 0; ni < 2; ++ni)
                    az[mi][ni] = __builtin_amdgcn_mfma_f32_16x16x32_bf16(
                        wy[mi], xv[ni][kt], az[mi][ni], 0, 0, 0);
        }
#pragma unroll
        for (int mi = 0; mi < 2; ++mi)
#pragma unroll
            for (int ni = 0; ni < 2; ++ni)
                *(f32x4_t*)(ldsT + (ni * 16 + lcol) * 256 + fsl + mi * 16 + qrow * 4)
                    = az[mi][ni];
    }
    __syncthreads();
    {   // coalesced bf16 store of Z
        const float4* src = (const float4*)ldsT;
        __bf16* dst = Zq + (size_t)bid * 32 * 256;
#pragma unroll
        for (int i = 0; i < 4; ++i) {
            float4 v = src[tid * 4 + i];
            bf16x4_t b = { (__bf16)v.x, (__bf16)v.y, (__bf16)v.z, (__bf16)v.w };
            *(bf16x4_t*)(dst + (size_t)(tid * 4 + i) * 4) = b;
        }
    }
}

// One tile of the main loop (round-9): GEMM2(t) reading Hr, with the H(t+1)
// assemble (VALU+ds_write into Hw) manually interleaved into the second half
// of the kt loop. Hr/Hw are DISTINCT __shared__ arrays (alias-free, so the
// compiler may schedule the assemble ops into the MFMA shadow), ping-ponged
// by the caller's 2x-unrolled loop.
// c = kt-4 is compile-time (unrolled) -> zf[c] is statically indexed.
__device__ __forceinline__ void tile_body(
    const int tt, const __bf16* __restrict__ Hr, __bf16* __restrict__ Hw,
    const float* __restrict__ lP, const __bf16* __restrict__ Zq,
    const int* __restrict__ senders, float* __restrict__ out,
    const bf16x8_t (&w2f)[8][4], const float (&bias2)[4],
    int& sn, const int n0, const int qrow, const int lcol,
    const int e5, const int fb, const int ktb, const int fsl)
{
    // ---- issue gather Z(tt+1) (consumed from kt=4 on; ~700 cyc cover) ----
    const bool pre = (tt + 1 < NT);
    bf16x8_t zf[4];
    if (pre) {
        const __bf16* zb = Zq + (size_t)sn * HD + fb;
#pragma unroll
        for (int c = 0; c < 4; ++c)
            zf[c] = *(const bf16x8_t*)(zb + c * 8);
    }
    int sn2 = 0;
    if (tt + 2 < NT) sn2 = senders[(n0 + tt + 2) * KNN + e5];

    const int na = pre ? tt + 1 : 0;
    const float* pfA = lP + na * 256 + fb;

    f32x4_t acc2[2][4];
#pragma unroll
    for (int mi = 0; mi < 2; ++mi)
#pragma unroll
        for (int ni = 0; ni < 4; ++ni)
            acc2[mi][ni] = (f32x4_t){0.f, 0.f, 0.f, 0.f};

    // ---- GEMM2 (K=256) with assemble chunks fused into kt=4..7 ----
#pragma unroll
    for (int kt = 0; kt < 8; ++kt) {
        bf16x8_t af[2];
#pragma unroll
        for (int mi = 0; mi < 2; ++mi)
            af[mi] = *(const bf16x8_t*)(Hr +
                (size_t)((kt * 4 + qrow) * 32 + mi * 16 + lcol) * 8);
#pragma unroll
        for (int mi = 0; mi < 2; ++mi)
#pragma unroll
            for (int ni = 0; ni < 4; ++ni)
                acc2[mi][ni] = __builtin_amdgcn_mfma_f32_16x16x32_bf16(
                    af[mi], w2f[kt][ni], acc2[mi][ni], 0, 0, 0);
        if (kt >= 4 && pre) {
            const int c = kt - 4;             // compile-time in unrolled loop
            f32x4_t p0 = *(const f32x4_t*)(pfA + c * 8);
            f32x4_t p1 = *(const f32x4_t*)(pfA + c * 8 + 4);
            bf16x8_t h;
#pragma unroll
            for (int j = 0; j < 4; ++j) {
                h[j]     = (__bf16)fmaxf(p0[j] + (float)zf[c][j],     0.f);
                h[j + 4] = (__bf16)fmaxf(p1[j] + (float)zf[c][j + 4], 0.f);
            }
            *(bf16x8_t*)(Hw + (size_t)((ktb * 4 + c) * 32 + e5) * 8) = h;
        }
    }

    // ---- epilogue: max over the node's 32 edges, +b2, store ----
#pragma unroll
    for (int ni = 0; ni < 4; ++ni) {
        float mx = -3.402823466e38f;
#pragma unroll
        for (int mi = 0; mi < 2; ++mi)
#pragma unroll
            for (int r = 0; r < 4; ++r)
                mx = fmaxf(mx, acc2[mi][ni][r]);
        mx = fmaxf(mx, __shfl_xor(mx, 16, 64));
        mx = fmaxf(mx, __shfl_xor(mx, 32, 64));
        if (qrow == 0)
            out[(size_t)(n0 + tt) * HD + fsl + ni * 16 + lcol] = mx + bias2[ni];
    }
    sn = sn2;
    __syncthreads();   // publishes Hw for tile tt+1
    // hazards: Hw's previous readers (GEMM2(tt-1)) finished before
    // barrier(tt-1); this body runs after it. Hw's new readers (GEMM2(tt+1))
    // run after this barrier.
}

// Main (round-9): round-5/8 structure, setprio removed (measured null),
// ldsH split into two distinct arrays + tile loop unrolled x2 so the
// H(t+1)-assemble interleaves into GEMM2(t)'s MFMA shadow (alias-free).
// 256 thr / 4 waves; wave w owns output-feature slice w*64 (w2f = 128 AGPR)
// and assembles slice w*64 of H. LDS 52 KB -> 2 blocks/CU at 2 waves/SIMD.
__global__ __launch_bounds__(256, 1) void ec_main(
    const __bf16* __restrict__ Zq,       // [NN][HD] bf16
    const int*   __restrict__ senders,   // [EE]
    const float* __restrict__ Pq,        // [NN][HD] fp32 (b1 folded in)
    const __bf16* __restrict__ w2t,      // [256 n][256 k]
    const float* __restrict__ b2,
    float* __restrict__ out)             // [NN][HD] fp32
{
    __shared__ __attribute__((aligned(16))) __bf16 ldsH0[8192];     // 16 KB H even
    __shared__ __attribute__((aligned(16))) __bf16 ldsH1[8192];     // 16 KB H odd
    __shared__ __attribute__((aligned(16))) float  ldsP[NT * 256];  // 20 KB fp32 P'

    const int tid  = threadIdx.x;
    const int lane = tid & 63;
    const int wave = tid >> 6;           // 0..3
    const int qrow = lane >> 4;
    const int lcol = lane & 15;
    const int blk  = blockIdx.x;
    const int fsl  = wave * 64;          // this wave's feature slice (assemble + GEMM2)
    const int e5   = lane & 31;          // edge id for gather/senders
    const int half = lane >> 5;          // feature half within slice (assemble)
    const int fb   = fsl + half * 32;    // assemble feature base (32-aligned)
    const int ktb  = fb >> 5;            // frag kt for assemble writes
    const int n0   = blk * NT;

    // ---- cooperative P' load: NT rows x 256 fp32 ----
    {
        const float4* src = (const float4*)(Pq + (size_t)n0 * 256);
        float4* dst = (float4*)ldsP;
#pragma unroll
        for (int i = 0; i < 5; ++i)
            dst[tid + i * 256] = src[tid + i * 256];
    }

    // ---- register-resident W2 slice (64 features): 128 regs ----
    bf16x8_t w2f[8][4];
#pragma unroll
    for (int kt = 0; kt < 8; ++kt)
#pragma unroll
        for (int ni = 0; ni < 4; ++ni)
            w2f[kt][ni] = *(const bf16x8_t*)(w2t + (size_t)(fsl + ni * 16 + lcol) * 256
                                                 + kt * 32 + qrow * 8);
    float bias2[4];
#pragma unroll
    for (int ni = 0; ni < 4; ++ni)
        bias2[ni] = b2[fsl + ni * 16 + lcol];

    // ---- prologue: gather Z(0); rolling sender-idx prefetch ----
    bf16x8_t zf[4];
    {
        int s0 = senders[n0 * KNN + e5];
        const __bf16* zb = Zq + (size_t)s0 * HD + fb;
#pragma unroll
        for (int c = 0; c < 4; ++c)
            zf[c] = *(const bf16x8_t*)(zb + c * 8);
    }
    int sn = senders[(n0 + 1) * KNN + e5];    // idx for tile 1

    __syncthreads();   // ldsP ready

    // ---- assemble H(0) -> ldsH0: h = relu(P'[node0] + Z) ----
    {
        const float* pf = ldsP + 0 * 256 + fb;
#pragma unroll
        for (int c = 0; c < 4; ++c) {
            f32x4_t p0 = *(const f32x4_t*)(pf + c * 8);
            f32x4_t p1 = *(const f32x4_t*)(pf + c * 8 + 4);
            bf16x8_t h;
#pragma unroll
            for (int j = 0; j < 4; ++j) {
                h[j]     = (__bf16)fmaxf(p0[j] + (float)zf[c][j],     0.f);
                h[j + 4] = (__bf16)fmaxf(p1[j] + (float)zf[c][j + 4], 0.f);
            }
            *(bf16x8_t*)(ldsH0 + (size_t)((ktb * 4 + c) * 32 + e5) * 8) = h;
        }
    }
    __syncthreads();   // ldsH0 published

#pragma unroll 1
    for (int tp = 0; tp < NT; tp += 2) {
        tile_body(tp,     ldsH0, ldsH1, ldsP, Zq, senders, out, w2f, bias2,
                  sn, n0, qrow, lcol, e5, fb, ktb, fsl);
        tile_body(tp + 1, ldsH1, ldsH0, ldsP, Zq, senders, out, w2f, bias2,
                  sn, n0, qrow, lcol, e5, fb, ktb, fsl);
    }
}

extern "C" void kernel_launch(void* const* d_in, const int* in_sizes, int n_in,
                              void* d_out, int out_size, void* d_ws, size_t ws_size,
                              hipStream_t stream) {
    const float* nf      = (const float*)d_in[0];
    const int*   senders = (const int*)d_in[1];
    // d_in[2] = receivers: implicit (repeat(arange(N), K)), unused
    const float* W1 = (const float*)d_in[3];
    const float* b1 = (const float*)d_in[4];
    const float* W2 = (const float*)d_in[5];
    const float* b2 = (const float*)d_in[6];

    __bf16* w1g = (__bf16*)d_ws;                 // 128 KB frag-ordered W1'
    __bf16* w2t = w1g + 256 * 256;               // 128 KB [n][k] bf16 W2^T
    __bf16* Zq  = w2t + 256 * 256;               // 10.24 MB bf16 Z = X*W1b
    float*  Pq  = (float*)(Zq + (size_t)NN * HD);// 20.48 MB fp32 P' = X*(W1a-W1b)+b1

    ec_wprep<<<256, 256, 0, stream>>>(W1, W2, w1g, w2t);
    ec_pz<<<PZB, 512, 0, stream>>>(nf, w1g, b1, Pq, Zq);
    ec_main<<<NBLK, 256, 0, stream>>>(Zq, senders, Pq, w2t, b2, (float*)d_out);
}